// Round 10
// baseline (130.330 us; speedup 1.0000x reference)
//
#include <hip/hip_runtime.h>

#define B_ 4
#define N_ 10000
#define D_ 64
#define C_ 2
#define E_ 160000
#define BC_ (B_ * C_)
#define SH2_ 7                  // 128 nodes per fine bucket
#define NB2_ 128
#define G2_ 79                  // ceil(10000/128)
#define CAPF_ 2560              // slots per (bc,bucket); mean 2048, +11 sigma
#define NBLK_ 125               // bucket-pass blocks per bc
#define EPT_ 5                  // edges per thread in bucket pass
#define EPB_ (256 * EPT_)       // 1280 edges per block
#define YBLK_ (BC_ * 40)        // y-phase blocks fused into gat_yb
#define EPS_ 1e-10f

// Fused kernel: blocks [0,YBLK_) compute per-node dots y1/y0; the remaining
// 1000 blocks run the coarse bucket pass with an in-LDS counting sort by
// bucket so global bpack writes are dense runs.
__global__ void gat_yb(const float* __restrict__ x, const float* __restrict__ wa,
                       float* __restrict__ y1, float* __restrict__ y0,
                       const int* __restrict__ eidx, int* __restrict__ gcount,
                       unsigned int* __restrict__ bpack) {
    int tid = threadIdx.x;
    if (blockIdx.x < YBLK_) {
        int bc = blockIdx.x & 7;
        int n  = (blockIdx.x >> 3) * 256 + tid;
        if (n >= N_) return;
        int b = bc / C_, c = bc % C_;
        const float4* xr = (const float4*)(x + ((size_t)b * N_ + n) * D_);
        const float4* w1 = (const float4*)(wa + (size_t)c * 2 * D_);
        const float4* w0 = w1 + D_ / 4;
        float a = 0.f, bb = 0.f;
#pragma unroll
        for (int i = 0; i < D_ / 4; ++i) {
            float4 xv = xr[i];
            float4 u = w1[i], v = w0[i];
            a  += xv.x * u.x + xv.y * u.y + xv.z * u.z + xv.w * u.w;
            bb += xv.x * v.x + xv.y * v.y + xv.z * v.z + xv.w * v.w;
        }
        y1[bc * N_ + n] = a;
        y0[bc * N_ + n] = bb;
        return;
    }
    // ---- bucket phase ----
    int bid = blockIdx.x - YBLK_;
    int bc  = bid & 7;
    int blk = bid >> 3;                     // 0..124
    const int2* ep = (const int2*)eidx + (size_t)bc * E_ + (size_t)blk * EPB_;
    __shared__ int sd[128];                 // hist then inclusive scan
    __shared__ int excl[G2_], cur[G2_], gbase[G2_];
    __shared__ unsigned int stage[EPB_];
    if (tid < 128) sd[tid] = 0;
    __syncthreads();
    unsigned int pk[EPT_];
    int gg[EPT_];
#pragma unroll
    for (int k = 0; k < EPT_; ++k) {
        int2 v = ep[k * 256 + tid];
        int g  = v.x >> SH2_;               // 0..78
        gg[k]  = g;
        pk[k]  = ((unsigned int)g << 21) |
                 ((unsigned int)(v.x & (NB2_ - 1)) << 14) |
                 (unsigned int)v.y;         // g:7 | ln:7 | i1:14
        atomicAdd(&sd[g], 1);
    }
    __syncthreads();
    int cnt = (tid < 128) ? sd[tid] : 0;
    for (int off = 1; off < 128; off <<= 1) {
        int t = (tid < 128 && tid >= off) ? sd[tid - off] : 0;
        __syncthreads();
        if (tid < 128) sd[tid] += t;
        __syncthreads();
    }
    if (tid < G2_) {
        int ex = sd[tid] - cnt;
        excl[tid]  = ex;
        cur[tid]   = ex;
        gbase[tid] = atomicAdd(&gcount[bc * G2_ + tid], cnt);
    }
    __syncthreads();
#pragma unroll
    for (int k = 0; k < EPT_; ++k) {
        int slot = atomicAdd(&cur[gg[k]], 1);
        stage[slot] = pk[k];
    }
    __syncthreads();
#pragma unroll
    for (int k = 0; k < EPT_; ++k) {
        int idx = k * 256 + tid;
        unsigned int p = stage[idx];
        int g     = p >> 21;
        int local = idx - excl[g];
        bpack[((size_t)bc * G2_ + g) * CAPF_ + gbase[g] + local] =
            (((p >> 14) & 127u) << 16) | (p & 16383u);
    }
}

// fine pass: one block per (bc,bucket) — denom via LDS float atomics on the
// coalesced ev pass, then counting-sort i1 only; writes sorted csr_i1 (u16),
// rs_s/rs_e, and yrd = {y1, 1/(den+eps)}
__global__ void gat_fine(const unsigned int* __restrict__ bpack,
                         const int* __restrict__ gcount,
                         const float* __restrict__ y1, const float* __restrict__ y0,
                         unsigned short* __restrict__ csr_i1,
                         int* __restrict__ rs_s, int* __restrict__ rs_e,
                         float2* __restrict__ yrd) {
    int bc = blockIdx.x & 7;
    int g  = blockIdx.x >> 3;               // 0..78
    int K  = gcount[bc * G2_ + g];
    int R  = (bc * G2_ + g) * CAPF_;        // absolute csr base for this bucket
    const unsigned int* bp = bpack + R;
    const float* y1p = y1 + bc * N_;
    int tid = threadIdx.x;

    __shared__ int   cnt[NB2_], excl[NB2_], cur[NB2_], sd[NB2_];
    __shared__ float y0l[NB2_], den[NB2_];
    __shared__ unsigned short li1[CAPF_];

    int node = g * NB2_ + tid;
    if (tid < NB2_) {
        cnt[tid] = 0;
        den[tid] = 0.f;
        y0l[tid] = (node < N_) ? y0[bc * N_ + node] : 0.f;
    }
    __syncthreads();

    for (int j = tid; j < K; j += 256) {
        unsigned int p = bp[j];
        int ln = p >> 16;
        int i1 = p & 0xffff;
        float sc = y1p[i1] + y0l[ln];
        float ev = __expf(sc > 0.f ? sc : 0.2f * sc);
        atomicAdd(&cnt[ln], 1);
        atomicAdd(&den[ln], ev);
    }
    __syncthreads();

    int v = 0;
    if (tid < NB2_) { v = cnt[tid]; sd[tid] = v; }
    __syncthreads();
    for (int off = 1; off < NB2_; off <<= 1) {
        int t = (tid < NB2_ && tid >= off) ? sd[tid - off] : 0;
        __syncthreads();
        if (tid < NB2_) sd[tid] += t;
        __syncthreads();
    }
    if (tid < NB2_) {
        int ex = sd[tid] - v;
        excl[tid] = ex;
        cur[tid]  = ex;
        if (node < N_) {
            rs_s[bc * N_ + node] = R + ex;
            rs_e[bc * N_ + node] = R + ex + v;
            yrd[bc * N_ + node]  = make_float2(y1p[node], 1.f / (den[tid] + EPS_));
        }
    }
    __syncthreads();

    for (int j = tid; j < K; j += 256) {
        unsigned int p = bp[j];
        int slot = atomicAdd(&cur[p >> 16], 1);
        li1[slot] = (unsigned short)(p & 0xffff);
    }
    __syncthreads();

    for (int j = tid; j < K; j += 256)
        csr_i1[R + j] = li1[j];
}

// wave per (b,n,c): lane = 16q+l; quad-edge float4 scheme — one dwordx4 load
// covers 4 edges' rows; meta {i1, wgt} staged in LDS; cross-group shfl reduce
__global__ void gat_acc(const float* __restrict__ x, const int* __restrict__ rs_s,
                        const int* __restrict__ rs_e,
                        const unsigned short* __restrict__ csr_i1,
                        const float2* __restrict__ yrd, const float* __restrict__ y0,
                        float* __restrict__ out) {
    int lane = threadIdx.x & 63;
    int w    = threadIdx.x >> 6;               // 0..3
    int b    = blockIdx.x & 3;                 // batch XCD-affine
    int nn   = blockIdx.x >> 2;                // 0..4999
    int n    = nn * 2 + (w >> 1);
    int c    = w & 1;
    int bc   = b * C_ + c;
    int q    = lane >> 4, l = lane & 15;
    const float4* xb4 = (const float4*)(x + (size_t)b * N_ * D_) + l;  // row a -> xb4[a*16]
    const float2* yrdp = yrd + bc * N_;
    int s = rs_s[bc * N_ + n], t = rs_e[bc * N_ + n];
    float y0n = y0[bc * N_ + n];
    __shared__ float2 meta[4][64];
    float4 acc4 = make_float4(0.f, 0.f, 0.f, 0.f);
    for (int base = s; base < t; base += 64) {
        int m = t - base; if (m > 64) m = 64;
        int a = 0; float wgt = 0.f;
        if (lane < m) {
            a = csr_i1[base + lane];               // coalesced u16
            float2 yr = yrdp[a];                   // packed {y1, rd} gather
            float sc = yr.x + y0n;
            wgt = __expf(sc > 0.f ? sc : 0.2f * sc) * yr.y;
        }
        meta[w][lane] = make_float2(__int_as_float(a), wgt);
        int mp = (m + 7) & ~7;                     // 2 quads per iter
        for (int j = 0; j < mp; j += 8) {
            float2 mA = meta[w][j + q];
            float2 mB = meta[w][j + 4 + q];
            float4 xA = xb4[__float_as_int(mA.x) * 16];
            float4 xB = xb4[__float_as_int(mB.x) * 16];
            acc4.x += mA.y * xA.x;
            acc4.y += mA.y * xA.y;
            acc4.z += mA.y * xA.z;
            acc4.w += mA.y * xA.w;
            acc4.x += mB.y * xB.x;
            acc4.y += mB.y * xB.y;
            acc4.z += mB.y * xB.z;
            acc4.w += mB.y * xB.w;
        }
    }
    // reduce across the 4 q-groups (lanes l, l+16, l+32, l+48)
#pragma unroll
    for (int off = 16; off < 64; off <<= 1) {
        acc4.x += __shfl_xor(acc4.x, off);
        acc4.y += __shfl_xor(acc4.y, off);
        acc4.z += __shfl_xor(acc4.z, off);
        acc4.w += __shfl_xor(acc4.w, off);
    }
    float4 sg;
    sg.x = 1.f / (1.f + __expf(-acc4.x));
    sg.y = 1.f / (1.f + __expf(-acc4.y));
    sg.z = 1.f / (1.f + __expf(-acc4.z));
    sg.w = 1.f / (1.f + __expf(-acc4.w));
    __shared__ float4 sh[2][16];
    if (c == 1 && q == 0) sh[w >> 1][l] = sg;
    __syncthreads();
    if (c == 0 && q == 0) {
        float4 o = sh[w >> 1][l];
        o.x += sg.x; o.y += sg.y; o.z += sg.z; o.w += sg.w;
        ((float4*)out)[((size_t)b * N_ + n) * 16 + l] = o;
    }
}

extern "C" void kernel_launch(void* const* d_in, const int* in_sizes, int n_in,
                              void* d_out, int out_size, void* d_ws, size_t ws_size,
                              hipStream_t stream) {
    const float* x    = (const float*)d_in[0];
    const int*   eidx = (const int*)d_in[1];
    const float* wa   = (const float*)d_in[2];
    float* out = (float*)d_out;

    int*    gcount = (int*)d_ws;                              // BC*G2 (pad 1024)
    float*  y1     = (float*)d_ws + 1024;                     // BC*N
    float*  y0     = y1 + BC_ * N_;                           // BC*N
    float2* yrd    = (float2*)(y0 + BC_ * N_);                // BC*N float2
    int*    rs_s   = (int*)(yrd + BC_ * N_);                  // BC*N
    int*    rs_e   = rs_s + BC_ * N_;                         // BC*N
    unsigned int* bpack = (unsigned int*)(rs_e + BC_ * N_);   // BC*G2*CAPF
    unsigned short* csr_i1 = (unsigned short*)(bpack + (size_t)BC_ * G2_ * CAPF_);

    hipMemsetAsync(gcount, 0, BC_ * G2_ * sizeof(int), stream);

    gat_yb  <<<YBLK_ + BC_ * NBLK_, 256, 0, stream>>>(x, wa, y1, y0, eidx, gcount, bpack);
    gat_fine<<<BC_ * G2_,           256, 0, stream>>>(bpack, gcount, y1, y0,
                                                      csr_i1, rs_s, rs_e, yrd);
    gat_acc <<<B_ * N_ / 2,         256, 0, stream>>>(x, rs_s, rs_e, csr_i1, yrd, y0, out);
}